// Round 1
// baseline (265.525 us; speedup 1.0000x reference)
//
#include <hip/hip_runtime.h>
#include <math.h>

// Sizes
#define HH 256
#define BB 128
#define OUTROW 1259   // 2+1+256+1000

// A(t) = sin(H*pi*r)*cos(pi*r)/(H*sin(pi*r)),  B(t) = sin(H*pi*r)/H,  r = t - round(t)
__device__ __forceinline__ void dirichlet_ab(float t, float& A, float& Bv) {
    float r = t - rintf(t);
    float s256 = sinpif(256.0f * r);
    Bv = s256 * (1.0f / 256.0f);
    if (fabsf(r) < 1e-6f) {
        A = 1.0f;
    } else {
        float sp = sinpif(r), cp = cospif(r);
        A = Bv * cp / sp;
    }
}

// One block per (b, c). 256 threads = 4 waves; wave w owns iy = {2w, 2w+1}.
// T[iy][q] = sum_p U[iy][p] * img[p][q]  (A-form and B-form), then
// pix[b, iy*8+ix, c] = sum_q Tc[iy][q]*Vc[ix][q] - Ts[iy][q]*Vs[ix][q].
__global__ __launch_bounds__(256) void interp_kernel(
    const float* __restrict__ image, const float* __restrict__ loc,
    const float* __restrict__ scl, float* __restrict__ pix)
{
    __shared__ float U[256 * 16];   // [p][w*4 + {A0,A1,B0,B1}]
    __shared__ float V[16 * 260];   // [ix][q] A ; [8+ix][q] B   (pad 260 vs banks)
    __shared__ float T[16 * 260];   // [iy][q] Tc ; [8+iy][q] Ts

    int bid = blockIdx.x;
    int b = bid / 3, c = bid % 3;
    int tid = threadIdx.x;
    float l0 = loc[2 * b], l1 = loc[2 * b + 1], sc = scl[b];

    // Build U (y-direction) and V (x-direction) weights; thread = p (or q)
    {
        int p = tid;
        float tp = (float)p * (1.0f / 256.0f);
        #pragma unroll
        for (int iy = 0; iy < 8; ++iy) {
            float A, Bv;
            float y = ((float)iy * 0.125f - l0) * sc;
            dirichlet_ab(y - tp, A, Bv);
            int w = iy >> 1, o = iy & 1;
            U[p * 16 + w * 4 + o] = A;
            U[p * 16 + w * 4 + 2 + o] = Bv;
            float x = ((float)iy * 0.125f - l1) * sc;   // iy reused as ix
            dirichlet_ab(x - tp, A, Bv);
            V[iy * 260 + p] = A;
            V[(8 + iy) * 260 + p] = Bv;
        }
    }
    __syncthreads();

    int wave = tid >> 6, lane = tid & 63;
    const float* img = image + (size_t)(b * 3 + c) * 65536 + lane * 4;

    float aA0[4] = {0, 0, 0, 0}, aA1[4] = {0, 0, 0, 0};
    float aB0[4] = {0, 0, 0, 0}, aB1[4] = {0, 0, 0, 0};
    #pragma unroll 4
    for (int p = 0; p < 256; ++p) {
        const float4 v = *(const float4*)(img + p * 256);
        const float4 u = *(const float4*)(&U[p * 16 + wave * 4]);
        aA0[0] += u.x * v.x; aA0[1] += u.x * v.y; aA0[2] += u.x * v.z; aA0[3] += u.x * v.w;
        aA1[0] += u.y * v.x; aA1[1] += u.y * v.y; aA1[2] += u.y * v.z; aA1[3] += u.y * v.w;
        aB0[0] += u.z * v.x; aB0[1] += u.z * v.y; aB0[2] += u.z * v.z; aB0[3] += u.z * v.w;
        aB1[0] += u.w * v.x; aB1[1] += u.w * v.y; aB1[2] += u.w * v.z; aB1[3] += u.w * v.w;
    }
    int iy0 = wave * 2;
    int q0 = lane * 4;
    #pragma unroll
    for (int j = 0; j < 4; ++j) {
        T[iy0 * 260 + q0 + j]       = aA0[j];
        T[(iy0 + 1) * 260 + q0 + j] = aA1[j];
        T[(8 + iy0) * 260 + q0 + j]     = aB0[j];
        T[(8 + iy0 + 1) * 260 + q0 + j] = aB1[j];
    }
    __syncthreads();

    // Epilogue: 4 threads per output point (split q), shfl-reduce.
    int n = tid >> 2, sub = tid & 3;
    int iy = n >> 3, ix = n & 7;
    float s = 0.f;
    #pragma unroll 8
    for (int i = 0; i < 64; ++i) {
        int q = sub + 4 * i;
        s += T[iy * 260 + q] * V[ix * 260 + q] - T[(8 + iy) * 260 + q] * V[(8 + ix) * 260 + q];
    }
    s += __shfl_xor(s, 1);
    s += __shfl_xor(s, 2);
    if (sub == 0) pix[(b * 64 + n) * 3 + c] = s;
}

// One block per batch row: full MLP chain + classifier + softmax.
__global__ __launch_bounds__(256) void mlp_kernel(
    const float* __restrict__ loc, const float* __restrict__ scl,
    const float* __restrict__ hidden, const float* __restrict__ pix,
    const float* __restrict__ w0, const float* __restrict__ b0,
    const float* __restrict__ rw, const float* __restrict__ rb,
    const float* __restrict__ wf, const float* __restrict__ bf,
    const float* __restrict__ cw0, const float* __restrict__ cb0,
    const float* __restrict__ crw, const float* __restrict__ crb,
    const float* __restrict__ cw1, const float* __restrict__ cb1,
    float* __restrict__ out)
{
    __shared__ float s_in[451];
    __shared__ float s_h[256];
    __shared__ float s_o[259];
    __shared__ float s_c[256];
    __shared__ float s_red[8];

    int b = blockIdx.x, tid = threadIdx.x;

    if (tid < 2) s_in[tid] = loc[2 * b + tid];
    if (tid == 2) s_in[2] = scl[b];
    if (tid < 192) s_in[3 + tid] = pix[b * 192 + tid];
    s_in[195 + tid] = hidden[b * 256 + tid];
    __syncthreads();

    // h0 = inp @ w0 + b0
    float acc = b0[tid];
    #pragma unroll 8
    for (int k = 0; k < 451; ++k) acc += s_in[k] * w0[k * 256 + tid];
    s_h[tid] = acc;
    __syncthreads();

    // 4 residual layers: h = relu(h@rw + rb + h)
    for (int i = 0; i < 4; ++i) {
        float a = rb[i * 256 + tid] + s_h[tid];
        const float* W = rw + (size_t)i * 65536;
        #pragma unroll 8
        for (int k = 0; k < 256; ++k) a += s_h[k] * W[k * 256 + tid];
        __syncthreads();
        s_h[tid] = fmaxf(a, 0.f);
        __syncthreads();
    }

    // out = tanh(h @ wf + bf), 259 wide
    for (int j = tid; j < 259; j += 256) {
        float a = bf[j];
        #pragma unroll 8
        for (int k = 0; k < 256; ++k) a += s_h[k] * wf[k * 259 + j];
        s_o[j] = tanhf(a);
    }
    __syncthreads();

    // residual state update
    float nh = hidden[b * 256 + tid] + s_o[3 + tid];
    float* orow = out + (size_t)b * OUTROW;
    if (tid < 2) orow[tid] = loc[2 * b + tid] + s_o[tid];
    if (tid == 2) orow[2] = scl[b] + s_o[2];
    orow[3 + tid] = nh;
    __syncthreads();   // everyone done reading s_h (in wf loop) before overwrite
    s_h[tid] = nh;
    __syncthreads();

    // c0 = relu(nh @ cw0 + cb0)
    float a = cb0[tid];
    #pragma unroll 8
    for (int k = 0; k < 256; ++k) a += s_h[k] * cw0[k * 256 + tid];
    s_c[tid] = fmaxf(a, 0.f);
    __syncthreads();

    // c1 = relu(c0 @ crw + crb + c0)
    a = crb[tid] + s_c[tid];
    #pragma unroll 8
    for (int k = 0; k < 256; ++k) a += s_c[k] * crw[k * 256 + tid];
    __syncthreads();
    s_c[tid] = fmaxf(a, 0.f);
    __syncthreads();

    // logits = c1 @ cw1 + cb1 (1000 wide), 4 cols per thread
    float lg[4];
    #pragma unroll
    for (int u = 0; u < 4; ++u) {
        int j = tid + 256 * u;
        lg[u] = (j < 1000) ? cb1[j] : -1e30f;
    }
    #pragma unroll 4
    for (int k = 0; k < 256; ++k) {
        float hv = s_c[k];
        const float* w = cw1 + (size_t)k * 1000 + tid;
        lg[0] += hv * w[0];
        lg[1] += hv * w[256];
        lg[2] += hv * w[512];
        if (tid < 232) lg[3] += hv * w[768];
    }

    // softmax over 1000
    float m = fmaxf(fmaxf(lg[0], lg[1]), fmaxf(lg[2], lg[3]));
    #pragma unroll
    for (int off = 1; off < 64; off <<= 1) m = fmaxf(m, __shfl_xor(m, off));
    if ((tid & 63) == 0) s_red[tid >> 6] = m;
    __syncthreads();
    m = fmaxf(fmaxf(s_red[0], s_red[1]), fmaxf(s_red[2], s_red[3]));

    float e[4], lsum = 0.f;
    #pragma unroll
    for (int u = 0; u < 4; ++u) { e[u] = expf(lg[u] - m); lsum += e[u]; }
    #pragma unroll
    for (int off = 1; off < 64; off <<= 1) lsum += __shfl_xor(lsum, off);
    if ((tid & 63) == 0) s_red[4 + (tid >> 6)] = lsum;
    __syncthreads();
    float total = s_red[4] + s_red[5] + s_red[6] + s_red[7];

    #pragma unroll
    for (int u = 0; u < 4; ++u) {
        int j = tid + 256 * u;
        if (j < 1000) orow[259 + j] = e[u] / total;
    }
}

extern "C" void kernel_launch(void* const* d_in, const int* in_sizes, int n_in,
                              void* d_out, int out_size, void* d_ws, size_t ws_size,
                              hipStream_t stream) {
    const float* image  = (const float*)d_in[0];
    const float* loc    = (const float*)d_in[1];
    const float* scl    = (const float*)d_in[2];
    const float* hidden = (const float*)d_in[3];
    const float* w0  = (const float*)d_in[4];
    const float* b0  = (const float*)d_in[5];
    const float* rw  = (const float*)d_in[6];
    const float* rb  = (const float*)d_in[7];
    const float* wf  = (const float*)d_in[8];
    const float* bf  = (const float*)d_in[9];
    const float* cw0 = (const float*)d_in[10];
    const float* cb0 = (const float*)d_in[11];
    const float* crw = (const float*)d_in[12];
    const float* crb = (const float*)d_in[13];
    const float* cw1 = (const float*)d_in[14];
    const float* cb1 = (const float*)d_in[15];

    float* pix = (float*)d_ws;   // 128*64*3 floats

    hipLaunchKernelGGL(interp_kernel, dim3(BB * 3), dim3(256), 0, stream,
                       image, loc, scl, pix);
    hipLaunchKernelGGL(mlp_kernel, dim3(BB), dim3(256), 0, stream,
                       loc, scl, hidden, pix,
                       w0, b0, rw, rb, wf, bf, cw0, cb0, crw, crb, cw1, cb1,
                       (float*)d_out);
}

// Round 2
// 102.451 us; speedup vs baseline: 2.5917x; 2.5917x over previous
//
#include <hip/hip_runtime.h>
#include <math.h>

// Sizes
#define HH 256
#define BB 128
#define OUTROW 1259   // 2+1+256+1000

// A(t) = sin(H*pi*r)*cos(pi*r)/(H*sin(pi*r)),  B(t) = sin(H*pi*r)/H,  r = t - round(t)
__device__ __forceinline__ void dirichlet_ab(float t, float& A, float& Bv) {
    float r = t - rintf(t);
    float s256 = sinpif(256.0f * r);
    Bv = s256 * (1.0f / 256.0f);
    if (fabsf(r) < 1e-6f) {
        A = 1.0f;
    } else {
        float sp = sinpif(r), cp = cospif(r);
        A = Bv * cp / sp;
    }
}

// One block per (b, c). 256 threads = 4 waves; wave w owns iy = {2w, 2w+1}.
__global__ __launch_bounds__(256) void interp_kernel(
    const float* __restrict__ image, const float* __restrict__ loc,
    const float* __restrict__ scl, float* __restrict__ pix)
{
    __shared__ float U[256 * 16];   // [p][w*4 + {A0,A1,B0,B1}]
    __shared__ float V[16 * 260];   // [ix][q] A ; [8+ix][q] B
    __shared__ float T[16 * 260];   // [iy][q] Tc ; [8+iy][q] Ts

    int bid = blockIdx.x;
    int b = bid / 3, c = bid % 3;
    int tid = threadIdx.x;
    float l0 = loc[2 * b], l1 = loc[2 * b + 1], sc = scl[b];

    {
        int p = tid;
        float tp = (float)p * (1.0f / 256.0f);
        #pragma unroll
        for (int iy = 0; iy < 8; ++iy) {
            float A, Bv;
            float y = ((float)iy * 0.125f - l0) * sc;
            dirichlet_ab(y - tp, A, Bv);
            int w = iy >> 1, o = iy & 1;
            U[p * 16 + w * 4 + o] = A;
            U[p * 16 + w * 4 + 2 + o] = Bv;
            float x = ((float)iy * 0.125f - l1) * sc;   // iy reused as ix
            dirichlet_ab(x - tp, A, Bv);
            V[iy * 260 + p] = A;
            V[(8 + iy) * 260 + p] = Bv;
        }
    }
    __syncthreads();

    int wave = tid >> 6, lane = tid & 63;
    const float* img = image + (size_t)(b * 3 + c) * 65536 + lane * 4;

    float aA0[4] = {0, 0, 0, 0}, aA1[4] = {0, 0, 0, 0};
    float aB0[4] = {0, 0, 0, 0}, aB1[4] = {0, 0, 0, 0};
    #pragma unroll 4
    for (int p = 0; p < 256; ++p) {
        const float4 v = *(const float4*)(img + p * 256);
        const float4 u = *(const float4*)(&U[p * 16 + wave * 4]);
        aA0[0] += u.x * v.x; aA0[1] += u.x * v.y; aA0[2] += u.x * v.z; aA0[3] += u.x * v.w;
        aA1[0] += u.y * v.x; aA1[1] += u.y * v.y; aA1[2] += u.y * v.z; aA1[3] += u.y * v.w;
        aB0[0] += u.z * v.x; aB0[1] += u.z * v.y; aB0[2] += u.z * v.z; aB0[3] += u.z * v.w;
        aB1[0] += u.w * v.x; aB1[1] += u.w * v.y; aB1[2] += u.w * v.z; aB1[3] += u.w * v.w;
    }
    int iy0 = wave * 2;
    int q0 = lane * 4;
    #pragma unroll
    for (int j = 0; j < 4; ++j) {
        T[iy0 * 260 + q0 + j]       = aA0[j];
        T[(iy0 + 1) * 260 + q0 + j] = aA1[j];
        T[(8 + iy0) * 260 + q0 + j]     = aB0[j];
        T[(8 + iy0 + 1) * 260 + q0 + j] = aB1[j];
    }
    __syncthreads();

    int n = tid >> 2, sub = tid & 3;
    int iy = n >> 3, ix = n & 7;
    float s = 0.f;
    #pragma unroll 8
    for (int i = 0; i < 64; ++i) {
        int q = sub + 4 * i;
        s += T[iy * 260 + q] * V[ix * 260 + q] - T[(8 + iy) * 260 + q] * V[(8 + ix) * 260 + q];
    }
    s += __shfl_xor(s, 1);
    s += __shfl_xor(s, 2);
    if (sub == 0) pix[(b * 64 + n) * 3 + c] = s;
}

// One block (1024 threads) per batch row. 4-way k-split per GEMV:
// sub = tid>>8 owns k = sub + 4t; partial sums reduced through LDS.
__global__ __launch_bounds__(1024) void mlp_kernel(
    const float* __restrict__ loc, const float* __restrict__ scl,
    const float* __restrict__ hidden, const float* __restrict__ pix,
    const float* __restrict__ w0, const float* __restrict__ b0,
    const float* __restrict__ rw, const float* __restrict__ rb,
    const float* __restrict__ wf, const float* __restrict__ bf,
    const float* __restrict__ cw0, const float* __restrict__ cb0,
    const float* __restrict__ crw, const float* __restrict__ crb,
    const float* __restrict__ cw1, const float* __restrict__ cb1,
    float* __restrict__ out)
{
    __shared__ float s_in[451];
    __shared__ float s_h[256];
    __shared__ float s_o[260];
    __shared__ float s_c[256];
    __shared__ float s_part[4 * 1024];
    __shared__ float s_red[32];

    int b = blockIdx.x, tid = threadIdx.x;
    int sub = tid >> 8, j = tid & 255;
    float* orow = out + (size_t)b * OUTROW;

    if (tid < 2) s_in[tid] = loc[2 * b + tid];
    if (tid == 2) s_in[2] = scl[b];
    if (tid >= 256 && tid < 448) s_in[3 + (tid - 256)] = pix[b * 192 + (tid - 256)];
    if (tid >= 512 && tid < 768) s_in[195 + (tid - 512)] = hidden[b * 256 + (tid - 512)];
    __syncthreads();

    // h0 = inp @ w0 + b0   (451 x 256)
    {
        float acc = 0.f;
        #pragma unroll 8
        for (int k = sub; k < 451; k += 4) acc += s_in[k] * w0[k * 256 + j];
        s_part[sub * 256 + j] = acc;
    }
    __syncthreads();
    if (tid < 256) {
        s_h[tid] = b0[tid] + s_part[tid] + s_part[256 + tid] + s_part[512 + tid] + s_part[768 + tid];
    }
    __syncthreads();

    // 4 residual layers: h = relu(h@rw + rb + h)
    for (int i = 0; i < 4; ++i) {
        const float* W = rw + (size_t)i * 65536;
        float acc = 0.f;
        #pragma unroll 8
        for (int t = 0; t < 64; ++t) {
            int k = sub + 4 * t;
            acc += s_h[k] * W[k * 256 + j];
        }
        s_part[sub * 256 + j] = acc;
        __syncthreads();
        if (tid < 256) {
            float a = rb[i * 256 + tid] + s_h[tid]
                    + s_part[tid] + s_part[256 + tid] + s_part[512 + tid] + s_part[768 + tid];
            s_h[tid] = fmaxf(a, 0.f);
        }
        __syncthreads();
    }

    // o = tanh(h @ wf + bf)   (256 x 259)
    {
        float acc = 0.f, acc2 = 0.f;
        #pragma unroll 8
        for (int t = 0; t < 64; ++t) {
            int k = sub + 4 * t;
            float hv = s_h[k];
            acc += hv * wf[k * 259 + j];
            if (j < 3) acc2 += hv * wf[k * 259 + 256 + j];
        }
        s_part[sub * 260 + j] = acc;
        if (j < 3) s_part[sub * 260 + 256 + j] = acc2;
    }
    __syncthreads();
    if (tid < 259) {
        float a = bf[tid] + s_part[tid] + s_part[260 + tid] + s_part[520 + tid] + s_part[780 + tid];
        s_o[tid] = tanhf(a);
    }
    __syncthreads();

    // residual state update + direct outputs
    if (tid < 256) {
        float nh = hidden[b * 256 + tid] + s_o[3 + tid];
        orow[3 + tid] = nh;
        s_h[tid] = nh;               // safe: everyone past wf-loop reads of s_h
    }
    if (tid == 256) orow[0] = loc[2 * b] + s_o[0];
    if (tid == 257) orow[1] = loc[2 * b + 1] + s_o[1];
    if (tid == 258) orow[2] = scl[b] + s_o[2];
    __syncthreads();

    // c0 = relu(nh @ cw0 + cb0)
    {
        float acc = 0.f;
        #pragma unroll 8
        for (int t = 0; t < 64; ++t) {
            int k = sub + 4 * t;
            acc += s_h[k] * cw0[k * 256 + j];
        }
        s_part[sub * 256 + j] = acc;
    }
    __syncthreads();
    if (tid < 256) {
        float a = cb0[tid] + s_part[tid] + s_part[256 + tid] + s_part[512 + tid] + s_part[768 + tid];
        s_c[tid] = fmaxf(a, 0.f);
    }
    __syncthreads();

    // c1 = relu(c0 @ crw + crb + c0)
    {
        float acc = 0.f;
        #pragma unroll 8
        for (int t = 0; t < 64; ++t) {
            int k = sub + 4 * t;
            acc += s_c[k] * crw[k * 256 + j];
        }
        s_part[sub * 256 + j] = acc;
    }
    __syncthreads();
    if (tid < 256) {
        float a = crb[tid] + s_c[tid]
                + s_part[tid] + s_part[256 + tid] + s_part[512 + tid] + s_part[768 + tid];
        s_c[tid] = fmaxf(a, 0.f);
    }
    __syncthreads();

    // logits = c1 @ cw1 + cb1  (256 x 1000); sub owns k-range [sub*64, sub*64+64)
    {
        float lg0 = 0.f, lg1 = 0.f, lg2 = 0.f, lg3 = 0.f;
        int k0 = sub * 64;
        #pragma unroll 4
        for (int t = 0; t < 64; ++t) {
            int k = k0 + t;
            float hv = s_c[k];
            const float* w = cw1 + (size_t)k * 1000 + j;
            lg0 += hv * w[0];
            lg1 += hv * w[256];
            lg2 += hv * w[512];
            if (j < 232) lg3 += hv * w[768];
        }
        s_part[sub * 1024 + j]        = lg0;
        s_part[sub * 1024 + 256 + j]  = lg1;
        s_part[sub * 1024 + 512 + j]  = lg2;
        s_part[sub * 1024 + 768 + j]  = lg3;
    }
    __syncthreads();

    float lgv = -1e30f;
    if (tid < 1000)
        lgv = cb1[tid] + s_part[tid] + s_part[1024 + tid] + s_part[2048 + tid] + s_part[3072 + tid];

    // softmax over 1000 across 16 waves
    int lane = tid & 63, wid = tid >> 6;
    float m = lgv;
    #pragma unroll
    for (int off = 1; off < 64; off <<= 1) m = fmaxf(m, __shfl_xor(m, off));
    if (lane == 0) s_red[wid] = m;
    __syncthreads();
    m = s_red[0];
    #pragma unroll
    for (int w = 1; w < 16; ++w) m = fmaxf(m, s_red[w]);

    float e = (tid < 1000) ? expf(lgv - m) : 0.f;
    float lsum = e;
    #pragma unroll
    for (int off = 1; off < 64; off <<= 1) lsum += __shfl_xor(lsum, off);
    if (lane == 0) s_red[16 + wid] = lsum;
    __syncthreads();
    float total = 0.f;
    #pragma unroll
    for (int w = 0; w < 16; ++w) total += s_red[16 + w];

    if (tid < 1000) orow[259 + tid] = e / total;
}

extern "C" void kernel_launch(void* const* d_in, const int* in_sizes, int n_in,
                              void* d_out, int out_size, void* d_ws, size_t ws_size,
                              hipStream_t stream) {
    const float* image  = (const float*)d_in[0];
    const float* loc    = (const float*)d_in[1];
    const float* scl    = (const float*)d_in[2];
    const float* hidden = (const float*)d_in[3];
    const float* w0  = (const float*)d_in[4];
    const float* b0  = (const float*)d_in[5];
    const float* rw  = (const float*)d_in[6];
    const float* rb  = (const float*)d_in[7];
    const float* wf  = (const float*)d_in[8];
    const float* bf  = (const float*)d_in[9];
    const float* cw0 = (const float*)d_in[10];
    const float* cb0 = (const float*)d_in[11];
    const float* crw = (const float*)d_in[12];
    const float* crb = (const float*)d_in[13];
    const float* cw1 = (const float*)d_in[14];
    const float* cb1 = (const float*)d_in[15];

    float* pix = (float*)d_ws;   // 128*64*3 floats

    hipLaunchKernelGGL(interp_kernel, dim3(BB * 3), dim3(256), 0, stream,
                       image, loc, scl, pix);
    hipLaunchKernelGGL(mlp_kernel, dim3(BB), dim3(1024), 0, stream,
                       loc, scl, hidden, pix,
                       w0, b0, rw, rb, wf, bf, cw0, cb0, crw, crb, cw1, cb1,
                       (float*)d_out);
}

// Round 3
// 98.399 us; speedup vs baseline: 2.6984x; 1.0412x over previous
//
#include <hip/hip_runtime.h>
#include <math.h>

// Sizes
#define HH 256
#define BB 128
#define OUTROW 1259   // 2+1+256+1000

// A(t) = sin(H*pi*r)*cos(pi*r)/(H*sin(pi*r)),  B(t) = sin(H*pi*r)/H,  r = t - round(t)
__device__ __forceinline__ void dirichlet_ab(float t, float& A, float& Bv) {
    float r = t - rintf(t);
    float s256 = sinpif(256.0f * r);
    Bv = s256 * (1.0f / 256.0f);
    if (fabsf(r) < 1e-6f) {
        A = 1.0f;
    } else {
        float sp = sinpif(r), cp = cospif(r);
        A = Bv * cp / sp;
    }
}

// One block per (b, c). 256 threads = 4 waves; wave w owns iy = {2w, 2w+1}.
__global__ __launch_bounds__(256) void interp_kernel(
    const float* __restrict__ image, const float* __restrict__ loc,
    const float* __restrict__ scl, float* __restrict__ pix)
{
    __shared__ float U[256 * 16];   // [p][w*4 + {A0,A1,B0,B1}]
    __shared__ float V[16 * 260];   // [ix][q] A ; [8+ix][q] B
    __shared__ float T[16 * 260];   // [iy][q] Tc ; [8+iy][q] Ts

    int bid = blockIdx.x;
    int b = bid / 3, c = bid % 3;
    int tid = threadIdx.x;
    float l0 = loc[2 * b], l1 = loc[2 * b + 1], sc = scl[b];

    {
        int p = tid;
        float tp = (float)p * (1.0f / 256.0f);
        #pragma unroll
        for (int iy = 0; iy < 8; ++iy) {
            float A, Bv;
            float y = ((float)iy * 0.125f - l0) * sc;
            dirichlet_ab(y - tp, A, Bv);
            int w = iy >> 1, o = iy & 1;
            U[p * 16 + w * 4 + o] = A;
            U[p * 16 + w * 4 + 2 + o] = Bv;
            float x = ((float)iy * 0.125f - l1) * sc;   // iy reused as ix
            dirichlet_ab(x - tp, A, Bv);
            V[iy * 260 + p] = A;
            V[(8 + iy) * 260 + p] = Bv;
        }
    }
    __syncthreads();

    int wave = tid >> 6, lane = tid & 63;
    const float* img = image + (size_t)(b * 3 + c) * 65536 + lane * 4;

    float aA0[4] = {0, 0, 0, 0}, aA1[4] = {0, 0, 0, 0};
    float aB0[4] = {0, 0, 0, 0}, aB1[4] = {0, 0, 0, 0};
    #pragma unroll 4
    for (int p = 0; p < 256; ++p) {
        const float4 v = *(const float4*)(img + p * 256);
        const float4 u = *(const float4*)(&U[p * 16 + wave * 4]);
        aA0[0] += u.x * v.x; aA0[1] += u.x * v.y; aA0[2] += u.x * v.z; aA0[3] += u.x * v.w;
        aA1[0] += u.y * v.x; aA1[1] += u.y * v.y; aA1[2] += u.y * v.z; aA1[3] += u.y * v.w;
        aB0[0] += u.z * v.x; aB0[1] += u.z * v.y; aB0[2] += u.z * v.z; aB0[3] += u.z * v.w;
        aB1[0] += u.w * v.x; aB1[1] += u.w * v.y; aB1[2] += u.w * v.z; aB1[3] += u.w * v.w;
    }
    int iy0 = wave * 2;
    int q0 = lane * 4;
    #pragma unroll
    for (int j = 0; j < 4; ++j) {
        T[iy0 * 260 + q0 + j]       = aA0[j];
        T[(iy0 + 1) * 260 + q0 + j] = aA1[j];
        T[(8 + iy0) * 260 + q0 + j]     = aB0[j];
        T[(8 + iy0 + 1) * 260 + q0 + j] = aB1[j];
    }
    __syncthreads();

    int n = tid >> 2, sub = tid & 3;
    int iy = n >> 3, ix = n & 7;
    float s = 0.f;
    #pragma unroll 8
    for (int i = 0; i < 64; ++i) {
        int q = sub + 4 * i;
        s += T[iy * 260 + q] * V[ix * 260 + q] - T[(8 + iy) * 260 + q] * V[(8 + ix) * 260 + q];
    }
    s += __shfl_xor(s, 1);
    s += __shfl_xor(s, 2);
    if (sub == 0) pix[(b * 64 + n) * 3 + c] = s;
}

// One block (1024 threads) per batch row. 16-way k-split, float4 weight loads.
// For 256-col layers: jg = tid&63 owns cols 4jg..4jg+3; sub = tid>>6 owns k = sub+16t.
// Per-wave, sub is uniform -> each vector load instruction covers 1KiB contiguous.
__global__ __launch_bounds__(1024) void mlp_kernel(
    const float* __restrict__ loc, const float* __restrict__ scl,
    const float* __restrict__ hidden, const float* __restrict__ pix,
    const float* __restrict__ w0, const float* __restrict__ b0,
    const float* __restrict__ rw, const float* __restrict__ rb,
    const float* __restrict__ wf, const float* __restrict__ bf,
    const float* __restrict__ cw0, const float* __restrict__ cb0,
    const float* __restrict__ crw, const float* __restrict__ crb,
    const float* __restrict__ cw1, const float* __restrict__ cb1,
    float* __restrict__ out)
{
    __shared__ float s_in[452];
    __shared__ float s_h[256];
    __shared__ float s_o[260];
    __shared__ float s_c[256];
    __shared__ float s_part[8192];   // 32 KiB: [16][256] / [16][260] / [8][1024]
    __shared__ float s_red[32];

    int b = blockIdx.x, tid = threadIdx.x;
    int jg = tid & 63, sub = tid >> 6;     // 16-way split
    int j4 = jg * 4;
    float* orow = out + (size_t)b * OUTROW;

    if (tid < 2) s_in[tid] = loc[2 * b + tid];
    if (tid == 2) s_in[2] = scl[b];
    if (tid >= 256 && tid < 448) s_in[3 + (tid - 256)] = pix[b * 192 + (tid - 256)];
    if (tid >= 512 && tid < 768) s_in[195 + (tid - 512)] = hidden[b * 256 + (tid - 512)];
    __syncthreads();

    // ---- h0 = inp @ w0 + b0   (451 x 256) ----
    {
        float4 acc = {0.f, 0.f, 0.f, 0.f};
        #pragma unroll
        for (int t = 0; t < 28; ++t) {
            int k = sub + 16 * t;
            float hv = s_in[k];
            float4 w = *(const float4*)(w0 + (size_t)k * 256 + j4);
            acc.x += hv * w.x; acc.y += hv * w.y; acc.z += hv * w.z; acc.w += hv * w.w;
        }
        if (sub < 3) {
            int k = 448 + sub;
            float hv = s_in[k];
            float4 w = *(const float4*)(w0 + (size_t)k * 256 + j4);
            acc.x += hv * w.x; acc.y += hv * w.y; acc.z += hv * w.z; acc.w += hv * w.w;
        }
        *(float4*)(&s_part[sub * 256 + j4]) = acc;
    }
    __syncthreads();
    if (tid < 256) {
        float a = b0[tid];
        #pragma unroll
        for (int s = 0; s < 16; ++s) a += s_part[s * 256 + tid];
        s_h[tid] = a;
    }
    __syncthreads();

    // ---- 4 residual layers: h = relu(h@rw + rb + h) ----
    for (int i = 0; i < 4; ++i) {
        const float* W = rw + (size_t)i * 65536;
        float4 acc = {0.f, 0.f, 0.f, 0.f};
        #pragma unroll
        for (int t = 0; t < 16; ++t) {
            int k = sub + 16 * t;
            float hv = s_h[k];
            float4 w = *(const float4*)(W + (size_t)k * 256 + j4);
            acc.x += hv * w.x; acc.y += hv * w.y; acc.z += hv * w.z; acc.w += hv * w.w;
        }
        *(float4*)(&s_part[sub * 256 + j4]) = acc;
        __syncthreads();
        if (tid < 256) {
            float a = rb[i * 256 + tid] + s_h[tid];
            #pragma unroll
            for (int s = 0; s < 16; ++s) a += s_part[s * 256 + tid];
            s_h[tid] = fmaxf(a, 0.f);   // safe: only thread tid touches s_h[tid] here
        }
        __syncthreads();
    }

    // ---- o = tanh(h @ wf + bf)   (256 x 259, stride 259 -> scalar loads) ----
    {
        float a0 = 0.f, a1 = 0.f, a2 = 0.f, a3 = 0.f, e = 0.f;
        #pragma unroll
        for (int t = 0; t < 16; ++t) {
            int k = sub + 16 * t;
            float hv = s_h[k];
            const float* w = wf + (size_t)k * 259 + j4;
            a0 += hv * w[0]; a1 += hv * w[1]; a2 += hv * w[2]; a3 += hv * w[3];
            if (jg < 3) e += hv * wf[(size_t)k * 259 + 256 + jg];
        }
        s_part[sub * 260 + j4 + 0] = a0;
        s_part[sub * 260 + j4 + 1] = a1;
        s_part[sub * 260 + j4 + 2] = a2;
        s_part[sub * 260 + j4 + 3] = a3;
        if (jg < 3) s_part[sub * 260 + 256 + jg] = e;
    }
    __syncthreads();
    if (tid < 259) {
        float a = bf[tid];
        #pragma unroll
        for (int s = 0; s < 16; ++s) a += s_part[s * 260 + tid];
        s_o[tid] = tanhf(a);
    }
    __syncthreads();

    // ---- residual state update + direct outputs ----
    if (tid < 256) {
        float nh = hidden[b * 256 + tid] + s_o[3 + tid];
        orow[3 + tid] = nh;
        s_h[tid] = nh;
    }
    if (tid == 256) orow[0] = loc[2 * b] + s_o[0];
    if (tid == 257) orow[1] = loc[2 * b + 1] + s_o[1];
    if (tid == 258) orow[2] = scl[b] + s_o[2];
    __syncthreads();

    // ---- c0 = relu(nh @ cw0 + cb0) ----
    {
        float4 acc = {0.f, 0.f, 0.f, 0.f};
        #pragma unroll
        for (int t = 0; t < 16; ++t) {
            int k = sub + 16 * t;
            float hv = s_h[k];
            float4 w = *(const float4*)(cw0 + (size_t)k * 256 + j4);
            acc.x += hv * w.x; acc.y += hv * w.y; acc.z += hv * w.z; acc.w += hv * w.w;
        }
        *(float4*)(&s_part[sub * 256 + j4]) = acc;
    }
    __syncthreads();
    if (tid < 256) {
        float a = cb0[tid];
        #pragma unroll
        for (int s = 0; s < 16; ++s) a += s_part[s * 256 + tid];
        s_c[tid] = fmaxf(a, 0.f);
    }
    __syncthreads();

    // ---- c1 = relu(c0 @ crw + crb + c0) ----
    {
        float4 acc = {0.f, 0.f, 0.f, 0.f};
        #pragma unroll
        for (int t = 0; t < 16; ++t) {
            int k = sub + 16 * t;
            float hv = s_c[k];
            float4 w = *(const float4*)(crw + (size_t)k * 256 + j4);
            acc.x += hv * w.x; acc.y += hv * w.y; acc.z += hv * w.z; acc.w += hv * w.w;
        }
        *(float4*)(&s_part[sub * 256 + j4]) = acc;
        __syncthreads();
        if (tid < 256) {
            float a = crb[tid] + s_c[tid];
            #pragma unroll
            for (int s = 0; s < 16; ++s) a += s_part[s * 256 + tid];
            s_c[tid] = fmaxf(a, 0.f);
        }
        __syncthreads();
    }

    // ---- logits = c1 @ cw1 + cb1  (256 x 1000) ----
    // 8-way k-split (sub8 = tid>>7), col groups: c4 = (tid&127)*4 and c4+512.
    {
        int sub8 = tid >> 7, jg8 = tid & 127;
        int c4 = jg8 * 4;
        float4 acc0 = {0.f, 0.f, 0.f, 0.f};
        float4 acc1 = {0.f, 0.f, 0.f, 0.f};
        #pragma unroll
        for (int t = 0; t < 32; ++t) {
            int k = sub8 + 8 * t;
            float hv = s_c[k];
            const float* w = cw1 + (size_t)k * 1000;
            float4 wa = *(const float4*)(w + c4);
            acc0.x += hv * wa.x; acc0.y += hv * wa.y; acc0.z += hv * wa.z; acc0.w += hv * wa.w;
            if (jg8 < 122) {
                float4 wb = *(const float4*)(w + c4 + 512);
                acc1.x += hv * wb.x; acc1.y += hv * wb.y; acc1.z += hv * wb.z; acc1.w += hv * wb.w;
            }
        }
        *(float4*)(&s_part[sub8 * 1024 + c4]) = acc0;
        if (jg8 < 122) *(float4*)(&s_part[sub8 * 1024 + 512 + c4]) = acc1;
    }
    __syncthreads();

    float lgv = -1e30f;
    if (tid < 1000) {
        float a = cb1[tid];
        #pragma unroll
        for (int s = 0; s < 8; ++s) a += s_part[s * 1024 + tid];
        lgv = a;
    }

    // ---- softmax over 1000 across 16 waves ----
    int lane = tid & 63, wid = tid >> 6;
    float m = lgv;
    #pragma unroll
    for (int off = 1; off < 64; off <<= 1) m = fmaxf(m, __shfl_xor(m, off));
    if (lane == 0) s_red[wid] = m;
    __syncthreads();
    m = s_red[0];
    #pragma unroll
    for (int w = 1; w < 16; ++w) m = fmaxf(m, s_red[w]);

    float e = (tid < 1000) ? expf(lgv - m) : 0.f;
    float lsum = e;
    #pragma unroll
    for (int off = 1; off < 64; off <<= 1) lsum += __shfl_xor(lsum, off);
    if (lane == 0) s_red[16 + wid] = lsum;
    __syncthreads();
    float total = 0.f;
    #pragma unroll
    for (int w = 0; w < 16; ++w) total += s_red[16 + w];

    if (tid < 1000) orow[259 + tid] = e / total;
}

extern "C" void kernel_launch(void* const* d_in, const int* in_sizes, int n_in,
                              void* d_out, int out_size, void* d_ws, size_t ws_size,
                              hipStream_t stream) {
    const float* image  = (const float*)d_in[0];
    const float* loc    = (const float*)d_in[1];
    const float* scl    = (const float*)d_in[2];
    const float* hidden = (const float*)d_in[3];
    const float* w0  = (const float*)d_in[4];
    const float* b0  = (const float*)d_in[5];
    const float* rw  = (const float*)d_in[6];
    const float* rb  = (const float*)d_in[7];
    const float* wf  = (const float*)d_in[8];
    const float* bf  = (const float*)d_in[9];
    const float* cw0 = (const float*)d_in[10];
    const float* cb0 = (const float*)d_in[11];
    const float* crw = (const float*)d_in[12];
    const float* crb = (const float*)d_in[13];
    const float* cw1 = (const float*)d_in[14];
    const float* cb1 = (const float*)d_in[15];

    float* pix = (float*)d_ws;   // 128*64*3 floats

    hipLaunchKernelGGL(interp_kernel, dim3(BB * 3), dim3(256), 0, stream,
                       image, loc, scl, pix);
    hipLaunchKernelGGL(mlp_kernel, dim3(BB), dim3(1024), 0, stream,
                       loc, scl, hidden, pix,
                       w0, b0, rw, rb, wf, bf, cw0, cb0, crw, crb, cw1, cb1,
                       (float*)d_out);
}

// Round 4
// 77.396 us; speedup vs baseline: 3.4307x; 1.2714x over previous
//
#include <hip/hip_runtime.h>
#include <math.h>

// Sizes
#define HH 256
#define BB 128
#define OUTROW 1259   // 2+1+256+1000

// A(t) = sin(H*pi*r)*cos(pi*r)/(H*sin(pi*r)),  B(t) = sin(H*pi*r)/H,  r = t - round(t)
__device__ __forceinline__ void dirichlet_ab(float t, float& A, float& Bv) {
    float r = t - rintf(t);
    float s256 = sinpif(256.0f * r);
    Bv = s256 * (1.0f / 256.0f);
    if (fabsf(r) < 1e-6f) {
        A = 1.0f;
    } else {
        float sp = sinpif(r), cp = cospif(r);
        A = Bv * cp / sp;
    }
}

// One block per (b, c). 256 threads = 4 waves; wave w owns iy = {2w, 2w+1}.
__global__ __launch_bounds__(256) void interp_kernel(
    const float* __restrict__ image, const float* __restrict__ loc,
    const float* __restrict__ scl, float* __restrict__ pix)
{
    __shared__ float U[256 * 16];   // [p][w*4 + {A0,A1,B0,B1}]
    __shared__ float V[16 * 260];   // [ix][q] A ; [8+ix][q] B
    __shared__ float T[16 * 260];   // [iy][q] Tc ; [8+iy][q] Ts

    int bid = blockIdx.x;
    int b = bid / 3, c = bid % 3;
    int tid = threadIdx.x;
    float l0 = loc[2 * b], l1 = loc[2 * b + 1], sc = scl[b];

    {
        int p = tid;
        float tp = (float)p * (1.0f / 256.0f);
        #pragma unroll
        for (int iy = 0; iy < 8; ++iy) {
            float A, Bv;
            float y = ((float)iy * 0.125f - l0) * sc;
            dirichlet_ab(y - tp, A, Bv);
            int w = iy >> 1, o = iy & 1;
            U[p * 16 + w * 4 + o] = A;
            U[p * 16 + w * 4 + 2 + o] = Bv;
            float x = ((float)iy * 0.125f - l1) * sc;   // iy reused as ix
            dirichlet_ab(x - tp, A, Bv);
            V[iy * 260 + p] = A;
            V[(8 + iy) * 260 + p] = Bv;
        }
    }
    __syncthreads();

    int wave = tid >> 6, lane = tid & 63;
    const float* img = image + (size_t)(b * 3 + c) * 65536 + lane * 4;

    float aA0[4] = {0, 0, 0, 0}, aA1[4] = {0, 0, 0, 0};
    float aB0[4] = {0, 0, 0, 0}, aB1[4] = {0, 0, 0, 0};
    #pragma unroll 4
    for (int p = 0; p < 256; ++p) {
        const float4 v = *(const float4*)(img + p * 256);
        const float4 u = *(const float4*)(&U[p * 16 + wave * 4]);
        aA0[0] += u.x * v.x; aA0[1] += u.x * v.y; aA0[2] += u.x * v.z; aA0[3] += u.x * v.w;
        aA1[0] += u.y * v.x; aA1[1] += u.y * v.y; aA1[2] += u.y * v.z; aA1[3] += u.y * v.w;
        aB0[0] += u.z * v.x; aB0[1] += u.z * v.y; aB0[2] += u.z * v.z; aB0[3] += u.z * v.w;
        aB1[0] += u.w * v.x; aB1[1] += u.w * v.y; aB1[2] += u.w * v.z; aB1[3] += u.w * v.w;
    }
    int iy0 = wave * 2;
    int q0 = lane * 4;
    #pragma unroll
    for (int j = 0; j < 4; ++j) {
        T[iy0 * 260 + q0 + j]       = aA0[j];
        T[(iy0 + 1) * 260 + q0 + j] = aA1[j];
        T[(8 + iy0) * 260 + q0 + j]     = aB0[j];
        T[(8 + iy0 + 1) * 260 + q0 + j] = aB1[j];
    }
    __syncthreads();

    int n = tid >> 2, sub = tid & 3;
    int iy = n >> 3, ix = n & 7;
    float s = 0.f;
    #pragma unroll 8
    for (int i = 0; i < 64; ++i) {
        int q = sub + 4 * i;
        s += T[iy * 260 + q] * V[ix * 260 + q] - T[(8 + iy) * 260 + q] * V[(8 + ix) * 260 + q];
    }
    s += __shfl_xor(s, 1);
    s += __shfl_xor(s, 2);
    if (sub == 0) pix[(b * 64 + n) * 3 + c] = s;
}

// One block (1024 threads) per batch row. 16-way k-split, float4 weight loads.
// __launch_bounds__(1024,1): 4 waves/SIMD -> 128-VGPR budget, no spills.
// Unroll factors capped so <=8 float4 loads are in flight per thread.
__global__ __launch_bounds__(1024, 1) void mlp_kernel(
    const float* __restrict__ loc, const float* __restrict__ scl,
    const float* __restrict__ hidden, const float* __restrict__ pix,
    const float* __restrict__ w0, const float* __restrict__ b0,
    const float* __restrict__ rw, const float* __restrict__ rb,
    const float* __restrict__ wf, const float* __restrict__ bf,
    const float* __restrict__ cw0, const float* __restrict__ cb0,
    const float* __restrict__ crw, const float* __restrict__ crb,
    const float* __restrict__ cw1, const float* __restrict__ cb1,
    float* __restrict__ out)
{
    __shared__ float s_in[452];
    __shared__ float s_h[256];
    __shared__ float s_o[260];
    __shared__ float s_c[256];
    __shared__ float s_part[8192];   // 32 KiB: [16][256] / [16][260] / [8][1024]
    __shared__ float s_red[32];

    int b = blockIdx.x, tid = threadIdx.x;
    int jg = tid & 63, sub = tid >> 6;     // 16-way split
    int j4 = jg * 4;
    float* orow = out + (size_t)b * OUTROW;

    if (tid < 2) s_in[tid] = loc[2 * b + tid];
    if (tid == 2) s_in[2] = scl[b];
    if (tid >= 256 && tid < 448) s_in[3 + (tid - 256)] = pix[b * 192 + (tid - 256)];
    if (tid >= 512 && tid < 768) s_in[195 + (tid - 512)] = hidden[b * 256 + (tid - 512)];
    __syncthreads();

    // ---- h0 = inp @ w0 + b0   (451 x 256) ----
    {
        float4 acc = {0.f, 0.f, 0.f, 0.f};
        #pragma unroll 7
        for (int t = 0; t < 28; ++t) {
            int k = sub + 16 * t;
            float hv = s_in[k];
            float4 w = *(const float4*)(w0 + (size_t)k * 256 + j4);
            acc.x += hv * w.x; acc.y += hv * w.y; acc.z += hv * w.z; acc.w += hv * w.w;
        }
        if (sub < 3) {
            int k = 448 + sub;
            float hv = s_in[k];
            float4 w = *(const float4*)(w0 + (size_t)k * 256 + j4);
            acc.x += hv * w.x; acc.y += hv * w.y; acc.z += hv * w.z; acc.w += hv * w.w;
        }
        *(float4*)(&s_part[sub * 256 + j4]) = acc;
    }
    __syncthreads();
    if (tid < 256) {
        float a = b0[tid];
        #pragma unroll
        for (int s = 0; s < 16; ++s) a += s_part[s * 256 + tid];
        s_h[tid] = a;
    }
    __syncthreads();

    // ---- 4 residual layers: h = relu(h@rw + rb + h) ----
    for (int i = 0; i < 4; ++i) {
        const float* W = rw + (size_t)i * 65536;
        float4 acc = {0.f, 0.f, 0.f, 0.f};
        #pragma unroll 8
        for (int t = 0; t < 16; ++t) {
            int k = sub + 16 * t;
            float hv = s_h[k];
            float4 w = *(const float4*)(W + (size_t)k * 256 + j4);
            acc.x += hv * w.x; acc.y += hv * w.y; acc.z += hv * w.z; acc.w += hv * w.w;
        }
        *(float4*)(&s_part[sub * 256 + j4]) = acc;
        __syncthreads();
        if (tid < 256) {
            float a = rb[i * 256 + tid] + s_h[tid];
            #pragma unroll
            for (int s = 0; s < 16; ++s) a += s_part[s * 256 + tid];
            s_h[tid] = fmaxf(a, 0.f);
        }
        __syncthreads();
    }

    // ---- o = tanh(h @ wf + bf)   (256 x 259, stride 259 -> scalar loads) ----
    {
        float a0 = 0.f, a1 = 0.f, a2 = 0.f, a3 = 0.f, e = 0.f;
        #pragma unroll 8
        for (int t = 0; t < 16; ++t) {
            int k = sub + 16 * t;
            float hv = s_h[k];
            const float* w = wf + (size_t)k * 259 + j4;
            a0 += hv * w[0]; a1 += hv * w[1]; a2 += hv * w[2]; a3 += hv * w[3];
            if (jg < 3) e += hv * wf[(size_t)k * 259 + 256 + jg];
        }
        s_part[sub * 260 + j4 + 0] = a0;
        s_part[sub * 260 + j4 + 1] = a1;
        s_part[sub * 260 + j4 + 2] = a2;
        s_part[sub * 260 + j4 + 3] = a3;
        if (jg < 3) s_part[sub * 260 + 256 + jg] = e;
    }
    __syncthreads();
    if (tid < 259) {
        float a = bf[tid];
        #pragma unroll
        for (int s = 0; s < 16; ++s) a += s_part[s * 260 + tid];
        s_o[tid] = tanhf(a);
    }
    __syncthreads();

    // ---- residual state update + direct outputs ----
    if (tid < 256) {
        float nh = hidden[b * 256 + tid] + s_o[3 + tid];
        orow[3 + tid] = nh;
        s_h[tid] = nh;
    }
    if (tid == 256) orow[0] = loc[2 * b] + s_o[0];
    if (tid == 257) orow[1] = loc[2 * b + 1] + s_o[1];
    if (tid == 258) orow[2] = scl[b] + s_o[2];
    __syncthreads();

    // ---- c0 = relu(nh @ cw0 + cb0) ----
    {
        float4 acc = {0.f, 0.f, 0.f, 0.f};
        #pragma unroll 8
        for (int t = 0; t < 16; ++t) {
            int k = sub + 16 * t;
            float hv = s_h[k];
            float4 w = *(const float4*)(cw0 + (size_t)k * 256 + j4);
            acc.x += hv * w.x; acc.y += hv * w.y; acc.z += hv * w.z; acc.w += hv * w.w;
        }
        *(float4*)(&s_part[sub * 256 + j4]) = acc;
    }
    __syncthreads();
    if (tid < 256) {
        float a = cb0[tid];
        #pragma unroll
        for (int s = 0; s < 16; ++s) a += s_part[s * 256 + tid];
        s_c[tid] = fmaxf(a, 0.f);
    }
    __syncthreads();

    // ---- c1 = relu(c0 @ crw + crb + c0) ----
    {
        float4 acc = {0.f, 0.f, 0.f, 0.f};
        #pragma unroll 8
        for (int t = 0; t < 16; ++t) {
            int k = sub + 16 * t;
            float hv = s_c[k];
            float4 w = *(const float4*)(crw + (size_t)k * 256 + j4);
            acc.x += hv * w.x; acc.y += hv * w.y; acc.z += hv * w.z; acc.w += hv * w.w;
        }
        *(float4*)(&s_part[sub * 256 + j4]) = acc;
        __syncthreads();
        if (tid < 256) {
            float a = crb[tid] + s_c[tid];
            #pragma unroll
            for (int s = 0; s < 16; ++s) a += s_part[s * 256 + tid];
            s_c[tid] = fmaxf(a, 0.f);
        }
        __syncthreads();
    }

    // ---- logits = c1 @ cw1 + cb1  (256 x 1000) ----
    // 8-way k-split (sub8 = tid>>7), col groups: c4 = (tid&127)*4 and c4+512.
    {
        int sub8 = tid >> 7, jg8 = tid & 127;
        int c4 = jg8 * 4;
        float4 acc0 = {0.f, 0.f, 0.f, 0.f};
        float4 acc1 = {0.f, 0.f, 0.f, 0.f};
        #pragma unroll 4
        for (int t = 0; t < 32; ++t) {
            int k = sub8 + 8 * t;
            float hv = s_c[k];
            const float* w = cw1 + (size_t)k * 1000;
            float4 wa = *(const float4*)(w + c4);
            acc0.x += hv * wa.x; acc0.y += hv * wa.y; acc0.z += hv * wa.z; acc0.w += hv * wa.w;
            if (jg8 < 122) {
                float4 wb = *(const float4*)(w + c4 + 512);
                acc1.x += hv * wb.x; acc1.y += hv * wb.y; acc1.z += hv * wb.z; acc1.w += hv * wb.w;
            }
        }
        *(float4*)(&s_part[sub8 * 1024 + c4]) = acc0;
        if (jg8 < 122) *(float4*)(&s_part[sub8 * 1024 + 512 + c4]) = acc1;
    }
    __syncthreads();

    float lgv = -1e30f;
    if (tid < 1000) {
        float a = cb1[tid];
        #pragma unroll
        for (int s = 0; s < 8; ++s) a += s_part[s * 1024 + tid];
        lgv = a;
    }

    // ---- softmax over 1000 across 16 waves ----
    int lane = tid & 63, wid = tid >> 6;
    float m = lgv;
    #pragma unroll
    for (int off = 1; off < 64; off <<= 1) m = fmaxf(m, __shfl_xor(m, off));
    if (lane == 0) s_red[wid] = m;
    __syncthreads();
    m = s_red[0];
    #pragma unroll
    for (int w = 1; w < 16; ++w) m = fmaxf(m, s_red[w]);

    float e = (tid < 1000) ? expf(lgv - m) : 0.f;
    float lsum = e;
    #pragma unroll
    for (int off = 1; off < 64; off <<= 1) lsum += __shfl_xor(lsum, off);
    if (lane == 0) s_red[16 + wid] = lsum;
    __syncthreads();
    float total = 0.f;
    #pragma unroll
    for (int w = 0; w < 16; ++w) total += s_red[16 + w];

    if (tid < 1000) orow[259 + tid] = e / total;
}

extern "C" void kernel_launch(void* const* d_in, const int* in_sizes, int n_in,
                              void* d_out, int out_size, void* d_ws, size_t ws_size,
                              hipStream_t stream) {
    const float* image  = (const float*)d_in[0];
    const float* loc    = (const float*)d_in[1];
    const float* scl    = (const float*)d_in[2];
    const float* hidden = (const float*)d_in[3];
    const float* w0  = (const float*)d_in[4];
    const float* b0  = (const float*)d_in[5];
    const float* rw  = (const float*)d_in[6];
    const float* rb  = (const float*)d_in[7];
    const float* wf  = (const float*)d_in[8];
    const float* bf  = (const float*)d_in[9];
    const float* cw0 = (const float*)d_in[10];
    const float* cb0 = (const float*)d_in[11];
    const float* crw = (const float*)d_in[12];
    const float* crb = (const float*)d_in[13];
    const float* cw1 = (const float*)d_in[14];
    const float* cb1 = (const float*)d_in[15];

    float* pix = (float*)d_ws;   // 128*64*3 floats

    hipLaunchKernelGGL(interp_kernel, dim3(BB * 3), dim3(256), 0, stream,
                       image, loc, scl, pix);
    hipLaunchKernelGGL(mlp_kernel, dim3(BB), dim3(1024), 0, stream,
                       loc, scl, hidden, pix,
                       w0, b0, rw, rb, wf, bf, cw0, cb0, crw, crb, cw1, cb1,
                       (float*)d_out);
}